// Round 2
// baseline (52.947 us; speedup 1.0000x reference)
//
#include <hip/hip_runtime.h>

// EMA scan: y_t = w*x_t + (1-w)*y_{t-1}, rows = B*C = 8192, T = 4096.
// fp32 in/out (reference tensors are float32). One wave per row.
// 8 fp32/lane per chunk (512 elems/wave/chunk, 8 chunks per row).

#define ROWS 8192
#define T_LEN 4096
#define ITERS 8                // 4096 / 512

__global__ __launch_bounds__(256) void ema_kernel(
    const float* __restrict__ x,     // [ROWS][T_LEN] fp32
    const float* __restrict__ init,  // [ROWS] fp32 (B,C,1 flattened)
    const float* __restrict__ wt,    // [1] fp32
    float* __restrict__ out)         // [ROWS][T_LEN] fp32
{
    const int lane = threadIdx.x & 63;
    const int wid  = threadIdx.x >> 6;
    const int row  = blockIdx.x * 4 + wid;

    float w = wt[0];
    w = fminf(fmaxf(w, 0.0f), 1.0f);
    const float a = 1.0f - w;

    // powers of a: apow[j] = a^j for j=0..8
    float apow[9];
    apow[0] = 1.0f;
    #pragma unroll
    for (int j = 1; j <= 8; ++j) apow[j] = apow[j - 1] * a;
    const float a8  = apow[8];
    const float m1  = a8;        // a^8
    const float m2  = m1 * m1;   // a^16
    const float m4  = m2 * m2;   // a^32
    const float m8  = m4 * m4;   // a^64
    const float m16 = m8 * m8;   // a^128
    const float m32 = m16 * m16; // a^256
    const float a512 = m32 * m32;

    // per-lane power a^(8*lane) via binary exponentiation (branch-free)
    float p8l = 1.0f;
    {
        float b = a8; int e = lane;
        #pragma unroll
        for (int k = 0; k < 6; ++k) {
            p8l *= (e & 1) ? b : 1.0f;
            b *= b; e >>= 1;
        }
    }

    float c = init[row];   // carry y_0

    const float4* xrow = reinterpret_cast<const float4*>(x) + (size_t)row * (T_LEN / 4);
    float4*       orow = reinterpret_cast<float4*>(out)     + (size_t)row * (T_LEN / 4);

    // prefetch chunk 0: each lane owns float4 slots (2*lane, 2*lane+1)
    float4 va = xrow[2 * lane];
    float4 vb = xrow[2 * lane + 1];

    #pragma unroll
    for (int it = 0; it < ITERS; ++it) {
        float4 na, nb;
        if (it + 1 < ITERS) {
            na = xrow[(it + 1) * 128 + 2 * lane];
            nb = xrow[(it + 1) * 128 + 2 * lane + 1];
        }

        float xv[8];
        xv[0] = va.x; xv[1] = va.y; xv[2] = va.z; xv[3] = va.w;
        xv[4] = vb.x; xv[5] = vb.y; xv[6] = vb.z; xv[7] = vb.w;

        // local zero-init scan: ls[j] = sum_{i<=j} a^(j-i) * w * xv[i]
        float ls[8];
        ls[0] = w * xv[0];
        #pragma unroll
        for (int j = 1; j < 8; ++j) ls[j] = fmaf(a, ls[j - 1], w * xv[j]);

        // wave-level Hillis-Steele affine scan of lane aggregates (ls[7]).
        float incl = ls[7];
        float t;
        t = __shfl_up(incl, 1);  if (lane >= 1)  incl = fmaf(m1,  t, incl);
        t = __shfl_up(incl, 2);  if (lane >= 2)  incl = fmaf(m2,  t, incl);
        t = __shfl_up(incl, 4);  if (lane >= 4)  incl = fmaf(m4,  t, incl);
        t = __shfl_up(incl, 8);  if (lane >= 8)  incl = fmaf(m8,  t, incl);
        t = __shfl_up(incl, 16); if (lane >= 16) incl = fmaf(m16, t, incl);
        t = __shfl_up(incl, 32); if (lane >= 32) incl = fmaf(m32, t, incl);

        float excl = __shfl_up(incl, 1);
        if (lane == 0) excl = 0.0f;

        // value entering this lane's first element: excl + a^(8*lane) * carry
        const float base = fmaf(p8l, c, excl);

        // y_j = ls[j] + a^(j+1) * base
        float4 oa, ob;
        oa.x = fmaf(apow[1], base, ls[0]);
        oa.y = fmaf(apow[2], base, ls[1]);
        oa.z = fmaf(apow[3], base, ls[2]);
        oa.w = fmaf(apow[4], base, ls[3]);
        ob.x = fmaf(apow[5], base, ls[4]);
        ob.y = fmaf(apow[6], base, ls[5]);
        ob.z = fmaf(apow[7], base, ls[6]);
        ob.w = fmaf(apow[8], base, ls[7]);

        orow[it * 128 + 2 * lane]     = oa;
        orow[it * 128 + 2 * lane + 1] = ob;

        // update carry for next chunk: y_last = incl_63 + a^512 * c
        float top = __shfl(incl, 63);
        c = fmaf(a512, c, top);
        va = na; vb = nb;
    }
}

extern "C" void kernel_launch(void* const* d_in, const int* in_sizes, int n_in,
                              void* d_out, int out_size, void* d_ws, size_t ws_size,
                              hipStream_t stream) {
    const float* x    = (const float*)d_in[0];
    const float* init = (const float*)d_in[1];
    const float* wt   = (const float*)d_in[2];
    float* out        = (float*)d_out;

    // 8192 rows, 1 wave (64 lanes) per row, 4 waves per 256-thread block
    dim3 grid(ROWS / 4), block(256);
    hipLaunchKernelGGL(ema_kernel, grid, block, 0, stream, x, init, wt, out);
}